// Round 1
// baseline (96.272 us; speedup 1.0000x reference)
//
#include <hip/hip_runtime.h>

#define H 224
#define W 224
#define NB 8
#define OUTC 16
#define FEAT 27
#define EPSV 0.001f

// ---------------------------------------------------------------------------
// Kernel 1: build the effective 16x27 complex filter bank from the circuit.
// One block, 32 threads. Thread j simulates the 5-qubit circuit applied to
// basis state e_j; the resulting amplitudes st[k] are column j of U.
// We keep rows k<16 (measured channels) and columns j<27 (nonzero features).
// ---------------------------------------------------------------------------
__global__ void build_M(const float* __restrict__ w, float2* __restrict__ M) {
    __shared__ float sre[32][33];
    __shared__ float sim_[32][33];
    const int j = threadIdx.x;  // basis state / column index

    for (int i = 0; i < 32; ++i) {
        sre[j][i] = (i == j) ? 1.0f : 0.0f;
        sim_[j][i] = 0.0f;
    }

    // Rot(phi, theta, omega) = RZ(omega) RY(theta) RZ(phi) on qubit q.
    // Qubit q lives at bit position (4 - q) of the flat index.
    for (int q = 0; q < 5; ++q) {
        float phi = w[q * 3 + 0];
        float th  = w[q * 3 + 1];
        float om  = w[q * 3 + 2];
        float ch = cosf(0.5f * th), sh = sinf(0.5f * th);
        float al = 0.5f * (phi + om), be = 0.5f * (phi - om);
        float ca = cosf(al), sa = sinf(al);
        float cb = cosf(be), sb = sinf(be);
        // U00 = e^{-i a} c ; U01 = -e^{+i b} s ; U10 = e^{-i b} s ; U11 = e^{+i a} c
        float u00r =  ca * ch, u00i = -sa * ch;
        float u01r = -cb * sh, u01i = -sb * sh;
        float u10r =  cb * sh, u10i = -sb * sh;
        float u11r =  ca * ch, u11i =  sa * ch;

        int m = 1 << (4 - q);
        for (int i = 0; i < 32; ++i) {
            if (i & m) continue;
            float a0r = sre[j][i],     a0i = sim_[j][i];
            float a1r = sre[j][i | m], a1i = sim_[j][i | m];
            sre[j][i]     = u00r * a0r - u00i * a0i + u01r * a1r - u01i * a1i;
            sim_[j][i]    = u00r * a0i + u00i * a0r + u01r * a1i + u01i * a1r;
            sre[j][i | m] = u10r * a0r - u10i * a0i + u11r * a1r - u11i * a1i;
            sim_[j][i | m]= u10r * a0i + u10i * a0r + u11r * a1i + u11i * a1r;
        }
    }

    // CNOT ring: control q, target (q+1)%5, applied sequentially.
    for (int q = 0; q < 5; ++q) {
        int mc = 1 << (4 - q);
        int mt = 1 << (4 - ((q + 1) % 5));
        for (int i = 0; i < 32; ++i) {
            if ((i & mc) && !(i & mt)) {
                int i2 = i | mt;
                float tr = sre[j][i]; sre[j][i] = sre[j][i2]; sre[j][i2] = tr;
                float ti = sim_[j][i]; sim_[j][i] = sim_[j][i2]; sim_[j][i2] = ti;
            }
        }
    }

    if (j < FEAT) {
        for (int k = 0; k < OUTC; ++k) {
            M[k * FEAT + j] = make_float2(sre[j][k], sim_[j][k]);
        }
    }
}

// ---------------------------------------------------------------------------
// Kernel 2: the fused "quantum conv". One thread per output pixel (b,y,x):
// 27-tap patch load (+EPS, zero-pad outside image), patch norm, 16 complex
// dot products with the uniform filter bank M (scalar loads -> SGPR FMAs),
// pointwise epilogue, 16 coalesced channel stores.
// 8*224*224 = 401408 = 1568 * 256 exactly, so no tail guard.
// ---------------------------------------------------------------------------
__global__ __launch_bounds__(256) void qconv_main(const float* __restrict__ x,
                                                  const float2* __restrict__ M,
                                                  float* __restrict__ out) {
    int p = blockIdx.x * 256 + threadIdx.x;
    int xx = p % W;
    int rest = p / W;
    int yy = rest % H;
    int b = rest / H;

    const float* xb = x + b * (3 * H * W);

    float v[FEAT];
    #pragma unroll
    for (int c = 0; c < 3; ++c) {
        #pragma unroll
        for (int ki = 0; ki < 3; ++ki) {
            #pragma unroll
            for (int kj = 0; kj < 3; ++kj) {
                int iy = yy + ki - 1;
                int ix = xx + kj - 1;
                float val = 0.0f;
                if (iy >= 0 && iy < H && ix >= 0 && ix < W)
                    val = xb[c * (H * W) + iy * W + ix];
                v[c * 9 + ki * 3 + kj] = val + EPSV;
            }
        }
    }

    float n2 = 0.0f;
    #pragma unroll
    for (int f = 0; f < FEAT; ++f) n2 = fmaf(v[f], v[f], n2);
    float scale = 8.0f / n2;  // OUT_C/2 = 8, divided by ||v||^2

    float* ob = out + b * (OUTC * H * W) + yy * W + xx;
    #pragma unroll
    for (int k = 0; k < OUTC; ++k) {
        float re = 0.0f, im = 0.0f;
        #pragma unroll
        for (int f = 0; f < FEAT; ++f) {
            float2 m = M[k * FEAT + f];  // uniform address -> scalar load
            re = fmaf(m.x, v[f], re);
            im = fmaf(m.y, v[f], im);
        }
        ob[k * (H * W)] = (re * re + im * im) * scale;
    }
}

extern "C" void kernel_launch(void* const* d_in, const int* in_sizes, int n_in,
                              void* d_out, int out_size, void* d_ws, size_t ws_size,
                              hipStream_t stream) {
    const float* x = (const float*)d_in[0];   // (8,3,224,224) f32
    const float* w = (const float*)d_in[1];   // (1,5,3) f32
    float* out = (float*)d_out;               // (8,16,224,224) f32
    float2* M = (float2*)d_ws;                // 16*27 float2 = 3456 B

    build_M<<<1, 32, 0, stream>>>(w, M);

    int pixels = out_size / OUTC;             // 401408
    int blocks = (pixels + 255) / 256;        // 1568
    qconv_main<<<blocks, 256, 0, stream>>>(x, M, out);
}

// Round 4
// 91.076 us; speedup vs baseline: 1.0570x; 1.0570x over previous
//
#include <hip/hip_runtime.h>

#define H 224
#define W 224
#define HW (H * W)          // 50176
#define OUTC 16
#define FEAT 27
#define EPSV 0.001f
// padded input: (8,3,226,228) so rows are 16B-aligned (228*4 = 912 = 57*16)
#define PH 226
#define PW 228
#define PLANE (PH * PW)     // 51528
#define NPAD (24 * PLANE)   // 1236672 floats = 4.95 MB
#define PAD_BLOCKS ((NPAD + 255) / 256)  // 4831

typedef float f4 __attribute__((ext_vector_type(4)));
typedef float f2 __attribute__((ext_vector_type(2)));

// ---------------------------------------------------------------------------
// prep: blocks 0..PAD_BLOCKS-1 write the padded (+EPS) input copy; the last
// block simulates the 5-qubit circuit on 32 basis states to build the
// effective 16x27 complex filter bank M.
// ---------------------------------------------------------------------------
__global__ __launch_bounds__(256) void prep(const float* __restrict__ x,
                                            const float* __restrict__ w,
                                            float* __restrict__ pbuf,
                                            float2* __restrict__ M) {
    if (blockIdx.x == gridDim.x - 1) {
        __shared__ float sre[32][33];
        __shared__ float sim_[32][33];
        const int j = threadIdx.x;
        if (j >= 32) return;

        for (int i = 0; i < 32; ++i) {
            sre[j][i] = (i == j) ? 1.0f : 0.0f;
            sim_[j][i] = 0.0f;
        }
        // Rot(phi,theta,omega) = RZ(omega) RY(theta) RZ(phi) on qubit q
        // (qubit q is bit (4-q) of the flat amplitude index)
        for (int q = 0; q < 5; ++q) {
            float phi = w[q * 3 + 0];
            float th  = w[q * 3 + 1];
            float om  = w[q * 3 + 2];
            float ch = cosf(0.5f * th), sh = sinf(0.5f * th);
            float al = 0.5f * (phi + om), be = 0.5f * (phi - om);
            float ca = cosf(al), sa = sinf(al);
            float cb = cosf(be), sb = sinf(be);
            float u00r =  ca * ch, u00i = -sa * ch;
            float u01r = -cb * sh, u01i = -sb * sh;
            float u10r =  cb * sh, u10i = -sb * sh;
            float u11r =  ca * ch, u11i =  sa * ch;
            int m = 1 << (4 - q);
            for (int i = 0; i < 32; ++i) {
                if (i & m) continue;
                float a0r = sre[j][i],     a0i = sim_[j][i];
                float a1r = sre[j][i | m], a1i = sim_[j][i | m];
                sre[j][i]      = u00r * a0r - u00i * a0i + u01r * a1r - u01i * a1i;
                sim_[j][i]     = u00r * a0i + u00i * a0r + u01r * a1i + u01i * a1r;
                sre[j][i | m]  = u10r * a0r - u10i * a0i + u11r * a1r - u11i * a1i;
                sim_[j][i | m] = u10r * a0i + u10i * a0r + u11r * a1i + u11i * a1r;
            }
        }
        // CNOT ring
        for (int q = 0; q < 5; ++q) {
            int mc = 1 << (4 - q);
            int mt = 1 << (4 - ((q + 1) % 5));
            for (int i = 0; i < 32; ++i) {
                if ((i & mc) && !(i & mt)) {
                    int i2 = i | mt;
                    float tr = sre[j][i]; sre[j][i] = sre[j][i2]; sre[j][i2] = tr;
                    float ti = sim_[j][i]; sim_[j][i] = sim_[j][i2]; sim_[j][i2] = ti;
                }
            }
        }
        if (j < FEAT) {
            for (int k = 0; k < OUTC; ++k)
                M[k * FEAT + j] = make_float2(sre[j][k], sim_[j][k]);
        }
        return;
    }

    int i = blockIdx.x * 256 + threadIdx.x;
    if (i >= NPAD) return;
    int px = i % PW;
    int rest = i / PW;
    int py = rest % PH;
    int cc = rest / PH;           // b*3 + c
    float val = EPSV;             // pad value = 0 + EPS
    int ix = px - 1, iy = py - 1;
    if (ix >= 0 && ix < W && iy >= 0 && iy < H)
        val = x[cc * HW + iy * W + ix] + EPSV;
    pbuf[i] = val;
}

// ---------------------------------------------------------------------------
// qconv: each thread computes 4 consecutive x-pixels for 8 of the 16 output
// channels (blockIdx bit 0 selects the channel half). Taps come from the
// padded buffer as aligned float4+float2 row loads (no branches); M comes
// from LDS with wave-uniform (broadcast) reads; stores are float4.
// ---------------------------------------------------------------------------
__global__ __launch_bounds__(256) void qconv(const float* __restrict__ pbuf,
                                             const float2* __restrict__ M,
                                             float* __restrict__ out) {
    __shared__ float2 Ms[OUTC * FEAT];  // 432 entries, 3456 B
    const int tid = threadIdx.x;
    Ms[tid] = M[tid];
    if (tid < OUTC * FEAT - 256) Ms[256 + tid] = M[256 + tid];
    __syncthreads();

    const int khalf = blockIdx.x & 1;                 // uniform per block
    const int g = (blockIdx.x >> 1) * 256 + tid;      // pixel-group id, 0..100351
    const int x4 = (g % 56) * 4;
    int rest = g / 56;
    const int y = rest % H;
    const int b = rest / H;

    // 3 channels x 3 rows x 6 columns of padded (+EPS) input
    float r[3][3][6];
    #pragma unroll
    for (int c = 0; c < 3; ++c) {
        #pragma unroll
        for (int ki = 0; ki < 3; ++ki) {
            const float* rp = pbuf + ((b * 3 + c) * PLANE) + (y + ki) * PW + x4;
            f4 a = *(const f4*)rp;        // 16B aligned by construction
            f2 t = *(const f2*)(rp + 4);
            r[c][ki][0] = a.x; r[c][ki][1] = a.y; r[c][ki][2] = a.z; r[c][ki][3] = a.w;
            r[c][ki][4] = t.x; r[c][ki][5] = t.y;
        }
    }

    float scale[4];
    #pragma unroll
    for (int p = 0; p < 4; ++p) {
        float n2 = 0.0f;
        #pragma unroll
        for (int c = 0; c < 3; ++c)
            #pragma unroll
            for (int ki = 0; ki < 3; ++ki)
                #pragma unroll
                for (int kj = 0; kj < 3; ++kj) {
                    float t = r[c][ki][p + kj];
                    n2 = fmaf(t, t, n2);
                }
        scale[p] = 8.0f / n2;             // OUT_C/2 = 8 over ||v||^2
    }

    float* ob = out + ((size_t)b * OUTC + khalf * 8) * HW + y * W + x4;
    #pragma unroll
    for (int kk = 0; kk < 8; ++kk) {
        float re[4] = {0, 0, 0, 0}, im[4] = {0, 0, 0, 0};
        #pragma unroll
        for (int f = 0; f < FEAT; ++f) {
            float2 m = Ms[(khalf * 8 + kk) * FEAT + f];  // uniform -> broadcast
            const int c = f / 9, rr = (f % 9) / 3, kj = f % 3;
            #pragma unroll
            for (int p = 0; p < 4; ++p) {
                float t = r[c][rr][p + kj];
                re[p] = fmaf(m.x, t, re[p]);
                im[p] = fmaf(m.y, t, im[p]);
            }
        }
        f4 o;
        o.x = (re[0] * re[0] + im[0] * im[0]) * scale[0];
        o.y = (re[1] * re[1] + im[1] * im[1]) * scale[1];
        o.z = (re[2] * re[2] + im[2] * im[2]) * scale[2];
        o.w = (re[3] * re[3] + im[3] * im[3]) * scale[3];
        *(f4*)(ob + kk * HW) = o;
    }
}

extern "C" void kernel_launch(void* const* d_in, const int* in_sizes, int n_in,
                              void* d_out, int out_size, void* d_ws, size_t ws_size,
                              hipStream_t stream) {
    const float* x = (const float*)d_in[0];   // (8,3,224,224) f32
    const float* w = (const float*)d_in[1];   // (1,5,3) f32
    float* out = (float*)d_out;               // (8,16,224,224) f32

    float2* M = (float2*)d_ws;                          // 3456 B
    float* pbuf = (float*)((char*)d_ws + 4096);         // padded input, 4.95 MB

    prep<<<PAD_BLOCKS + 1, 256, 0, stream>>>(x, w, pbuf, M);

    // 100352 pixel-groups (4 px each) x 2 channel-halves = 784 blocks of 256
    qconv<<<784, 256, 0, stream>>>(pbuf, M, out);
}

// Round 6
// 81.233 us; speedup vs baseline: 1.1851x; 1.1212x over previous
//
#include <hip/hip_runtime.h>

#define H 224
#define W 224
#define HW (H * W)          // 50176
#define OUTC 16
#define FEAT 27
#define EPSV 0.001f

typedef float f4 __attribute__((ext_vector_type(4)));

// ---------------------------------------------------------------------------
// Single fused kernel. Per block:
//  1) 256-thread parallel simulation of the 5-qubit circuit on all 32 basis
//     states (32x32 complex amplitude matrix in LDS). 5 Rot gates; the CNOT
//     ring is a pure basis permutation, folded into the Ms gather (no swaps).
//  2) Conv phase: each thread computes 4 consecutive x-pixels for 8 output
//     channels (blockIdx bit 0 = channel half). Taps read directly from x
//     (aligned f4 + 2 edge scalars per row, predicated at image borders);
//     M read from LDS with wave-uniform broadcast; f4 stores.
// 784 blocks x 256 threads; 8*224*224 px, 4 px/thread, 2 channel halves.
// ---------------------------------------------------------------------------
__global__ __launch_bounds__(256) void qconv_fused(const float* __restrict__ x,
                                                   const float* __restrict__ w,
                                                   float* __restrict__ out) {
    __shared__ float2 amp[32][32];      // [basis column j][amplitude i]
    __shared__ float2 Ms[8 * FEAT];     // this block's 8 channels x 27 feats

    const int tid = threadIdx.x;
    const int khalf = blockIdx.x & 1;

    // ---- init: column j = basis state e_j ----
    #pragma unroll
    for (int e = tid; e < 1024; e += 256) {
        int j = e >> 5, i = e & 31;
        amp[j][i] = make_float2((i == j) ? 1.0f : 0.0f, 0.0f);
    }
    __syncthreads();

    // ---- 5 Rot gates: Rot(phi,theta,omega) = RZ(omega) RY(theta) RZ(phi),
    //      qubit q lives at bit (4-q). 512 disjoint pairs, 2 per thread. ----
    #pragma unroll
    for (int q = 0; q < 5; ++q) {
        float phi = w[q * 3 + 0], th = w[q * 3 + 1], om = w[q * 3 + 2];
        float sh, ch; sincosf(0.5f * th, &sh, &ch);
        float sa, ca; sincosf(0.5f * (phi + om), &sa, &ca);
        float sb, cb; sincosf(0.5f * (phi - om), &sb, &cb);
        float u00r =  ca * ch, u00i = -sa * ch;
        float u01r = -cb * sh, u01i = -sb * sh;
        float u10r =  cb * sh, u10i = -sb * sh;
        float u11r =  ca * ch, u11i =  sa * ch;
        const int m = 1 << (4 - q);
        #pragma unroll
        for (int rep = 0; rep < 2; ++rep) {
            int pidx = tid + rep * 256;          // 0..511
            int j = pidx >> 4, pp = pidx & 15;
            int i0 = ((pp & ~(m - 1)) << 1) | (pp & (m - 1));
            int i1 = i0 | m;
            float2 a0 = amp[j][i0], a1 = amp[j][i1];
            float2 n0, n1;
            n0.x = u00r * a0.x - u00i * a0.y + u01r * a1.x - u01i * a1.y;
            n0.y = u00r * a0.y + u00i * a0.x + u01r * a1.y + u01i * a1.x;
            n1.x = u10r * a0.x - u10i * a0.y + u11r * a1.x - u11i * a1.y;
            n1.y = u10r * a0.y + u10i * a0.x + u11r * a1.y + u11i * a1.x;
            amp[j][i0] = n0; amp[j][i1] = n1;
        }
        __syncthreads();
    }

    // ---- gather Ms with the CNOT-ring permutation folded in:
    //      final[k] = pre[C0(C1(C2(C3(C4(k)))))], Cq: i ^= ((i>>pc)&1)<<pt ----
    for (int e = tid; e < 8 * FEAT; e += 256) {  // 216 entries
        int kk = e / FEAT, j = e % FEAT;
        int i = khalf * 8 + kk;
        #pragma unroll
        for (int q = 4; q >= 0; --q) {
            int pc = 4 - q, pt = 4 - ((q + 1) % 5);
            i ^= ((i >> pc) & 1) << pt;
        }
        Ms[e] = amp[j][i];
    }
    __syncthreads();

    // ---- conv phase ----
    const int g = (blockIdx.x >> 1) * 256 + tid;   // pixel-group id, 0..100351
    const int x4 = (g % 56) * 4;
    int rest = g / 56;
    const int y = rest % H;
    const int b = rest / H;
    const float* xb = x + b * 3 * HW;

    // 3 channels x 3 rows x 6 columns, +EPS, zero outside the image
    float r[3][3][6];
    #pragma unroll
    for (int c = 0; c < 3; ++c) {
        #pragma unroll
        for (int ki = 0; ki < 3; ++ki) {
            int iy = y + ki - 1;
            bool rowok = (iy >= 0) && (iy < H);
            const float* rp = xb + c * HW + iy * W + x4;
            f4 mid = rowok ? *(const f4*)rp : (f4){0.f, 0.f, 0.f, 0.f};
            float left  = (rowok && x4 > 0)   ? rp[-1] : 0.0f;
            float right = (rowok && x4 < 220) ? rp[4]  : 0.0f;
            r[c][ki][0] = left  + EPSV;
            r[c][ki][1] = mid.x + EPSV;
            r[c][ki][2] = mid.y + EPSV;
            r[c][ki][3] = mid.z + EPSV;
            r[c][ki][4] = mid.w + EPSV;
            r[c][ki][5] = right + EPSV;
        }
    }

    float scale[4];
    #pragma unroll
    for (int p = 0; p < 4; ++p) {
        float n2 = 0.0f;
        #pragma unroll
        for (int c = 0; c < 3; ++c)
            #pragma unroll
            for (int ki = 0; ki < 3; ++ki)
                #pragma unroll
                for (int kj = 0; kj < 3; ++kj) {
                    float t = r[c][ki][p + kj];
                    n2 = fmaf(t, t, n2);
                }
        scale[p] = 8.0f / n2;              // OUT_C/2 = 8 over ||v||^2
    }

    float* ob = out + ((size_t)b * OUTC + khalf * 8) * HW + y * W + x4;
    #pragma unroll
    for (int kk = 0; kk < 8; ++kk) {
        float re[4] = {0, 0, 0, 0}, im[4] = {0, 0, 0, 0};
        #pragma unroll
        for (int f = 0; f < FEAT; ++f) {
            float2 m = Ms[kk * FEAT + f];  // uniform -> LDS broadcast
            const int c = f / 9, rr = (f % 9) / 3, kj = f % 3;
            #pragma unroll
            for (int p = 0; p < 4; ++p) {
                float t = r[c][rr][p + kj];
                re[p] = fmaf(m.x, t, re[p]);
                im[p] = fmaf(m.y, t, im[p]);
            }
        }
        f4 o;
        o.x = (re[0] * re[0] + im[0] * im[0]) * scale[0];
        o.y = (re[1] * re[1] + im[1] * im[1]) * scale[1];
        o.z = (re[2] * re[2] + im[2] * im[2]) * scale[2];
        o.w = (re[3] * re[3] + im[3] * im[3]) * scale[3];
        *(f4*)(ob + kk * HW) = o;
    }
}

extern "C" void kernel_launch(void* const* d_in, const int* in_sizes, int n_in,
                              void* d_out, int out_size, void* d_ws, size_t ws_size,
                              hipStream_t stream) {
    const float* x = (const float*)d_in[0];   // (8,3,224,224) f32
    const float* w = (const float*)d_in[1];   // (1,5,3) f32
    float* out = (float*)d_out;               // (8,16,224,224) f32
    (void)d_ws; (void)ws_size;

    // 100352 pixel-groups (4 px each) x 2 channel-halves = 784 blocks of 256
    qconv_fused<<<784, 256, 0, stream>>>(x, w, out);
}